// Round 5
// baseline (9177.924 us; speedup 1.0000x reference)
//
#include <hip/hip_runtime.h>
#include <stdint.h>

#define ALPHA 64
#define EDIM 1024
#define G4 4096
#define BATCH 4096
#define TLEN 20
#define BOS_TOK 64
#define PAD_TOK 65
#define EOS_TOK 0

// ---------------------------------------------------------------------------
// Threefry-2x32, 20 rounds — exact transcription of jax/_src/prng.py
// ---------------------------------------------------------------------------
__device__ __forceinline__ void threefry2x32(uint32_t k0, uint32_t k1,
                                             uint32_t& x0, uint32_t& x1) {
  uint32_t ks[3] = {k0, k1, k0 ^ k1 ^ 0x1BD11BDAu};
  const int rot0[4] = {13, 15, 26, 6};
  const int rot1[4] = {17, 29, 16, 24};
  x0 += ks[0];
  x1 += ks[1];
#pragma unroll
  for (int i = 0; i < 5; ++i) {
    const int* rr = (i & 1) ? rot1 : rot0;
#pragma unroll
    for (int j = 0; j < 4; ++j) {
      x0 += x1;
      x1 = (x1 << rr[j]) | (x1 >> (32 - rr[j]));
      x1 ^= x0;
    }
    x0 += ks[(i + 1) % 3];
    x1 += ks[(i + 2) % 3] + (uint32_t)(i + 1);
  }
}

// ---------------------------------------------------------------------------
// jax_threefry_partitionable=True (default since jax 0.4.30) semantics:
//   split(key, 20) foldlike: keys[t] = threefry(key, (hi=0, lo=t)) -> (x0', x1')
//   random_bits 32-bit:      bits[m] = x0' ^ x1' of threefry(key, (hi=0, lo=m))
// ---------------------------------------------------------------------------
__global__ void init_kernel(uint32_t* __restrict__ keyA, uint32_t* __restrict__ keyB,
                            int* __restrict__ last, int* __restrict__ stopped,
                            double* __restrict__ ent_sum, int* __restrict__ len_sum) {
  int i = blockIdx.x * 256 + threadIdx.x;
  if (i < BATCH) {
    last[i] = BOS_TOK;
    stopped[i] = 0;
    ent_sum[i] = 0.0;
    len_sum[i] = 0;
  }
  if (i < TLEN) {
    uint32_t x0 = 0u, x1 = (uint32_t)i;   // 64-bit iota elem i -> (hi=0, lo=i)
    threefry2x32(0u, 42u, x0, x1);        // key(42) = (0, 42)
    keyA[i] = x0;
    keyB[i] = x1;
  }
}

// W_act [64][1024] -> WactT [1024][64]
__global__ void transpose_wact(const float* __restrict__ W, float* __restrict__ Wt) {
  int i = blockIdx.x * 256 + threadIdx.x;
  if (i < ALPHA * EDIM) {
    int a = i >> 10, k = i & 1023;
    Wt[(size_t)k * ALPHA + a] = W[i];
  }
}

// ---------------------------------------------------------------------------
// f32 NT GEMM, single-accumulator ascending-k fmaf chain per element
// (bit-matches a BLAS sgemm microkernel's per-element reduction order).
// MODE 0: C = A@B^T (+bias1[n]) — bias1 may be null (raw s1 table)
// MODE 1: C = (s1[last[m]][n] + acc) + (b_ih[n] + b_hh[n])   — ref assoc.
// 128x128 tile, BK=16, 256 threads, 8x8 per thread
// ---------------------------------------------------------------------------
template <int MODE>
__global__ __launch_bounds__(256) void gemm_nt(
    const float* __restrict__ A, const float* __restrict__ Bw, float* __restrict__ C,
    int M, int N, int K,
    const float* __restrict__ bias1, const float* __restrict__ bias2,
    const float* __restrict__ eg, const int* __restrict__ lastIdx) {
  __shared__ float As[16][132];
  __shared__ float Bs[16][132];
  const int t = threadIdx.x;
  const int bm = blockIdx.y * 128;
  const int bn = blockIdx.x * 128;
  const int tx = t & 15, ty = t >> 4;

  float acc[8][8];
#pragma unroll
  for (int i = 0; i < 8; ++i)
#pragma unroll
    for (int j = 0; j < 8; ++j) acc[i][j] = 0.0f;

  const int sr = t >> 1;          // 0..127 (tile row)
  const int sc = (t & 1) << 3;    // 0 or 8 (k offset)
  const float* ap = A + (size_t)(bm + sr) * K + sc;
  const float* bp = Bw + (size_t)(bn + sr) * K + sc;
  const bool aok = (bm + sr) < M;

  for (int k0 = 0; k0 < K; k0 += 16) {
    float4 av0 = {0.f, 0.f, 0.f, 0.f}, av1 = {0.f, 0.f, 0.f, 0.f};
    if (aok) {
      av0 = *(const float4*)(ap + k0);
      av1 = *(const float4*)(ap + k0 + 4);
    }
    float4 bv0 = *(const float4*)(bp + k0);
    float4 bv1 = *(const float4*)(bp + k0 + 4);
    __syncthreads();
    As[sc + 0][sr] = av0.x; As[sc + 1][sr] = av0.y; As[sc + 2][sr] = av0.z; As[sc + 3][sr] = av0.w;
    As[sc + 4][sr] = av1.x; As[sc + 5][sr] = av1.y; As[sc + 6][sr] = av1.z; As[sc + 7][sr] = av1.w;
    Bs[sc + 0][sr] = bv0.x; Bs[sc + 1][sr] = bv0.y; Bs[sc + 2][sr] = bv0.z; Bs[sc + 3][sr] = bv0.w;
    Bs[sc + 4][sr] = bv1.x; Bs[sc + 5][sr] = bv1.y; Bs[sc + 6][sr] = bv1.z; Bs[sc + 7][sr] = bv1.w;
    __syncthreads();
#pragma unroll
    for (int k = 0; k < 16; ++k) {   // ascending k within chunk; chunks ascending
      float4 a0 = *(const float4*)&As[k][ty * 4];
      float4 a1 = *(const float4*)&As[k][ty * 4 + 64];
      float4 b0 = *(const float4*)&Bs[k][tx * 4];
      float4 b1 = *(const float4*)&Bs[k][tx * 4 + 64];
      float ar[8] = {a0.x, a0.y, a0.z, a0.w, a1.x, a1.y, a1.z, a1.w};
      float br[8] = {b0.x, b0.y, b0.z, b0.w, b1.x, b1.y, b1.z, b1.w};
#pragma unroll
      for (int i = 0; i < 8; ++i)
#pragma unroll
        for (int j = 0; j < 8; ++j) acc[i][j] = fmaf(ar[i], br[j], acc[i][j]);
    }
  }

#pragma unroll
  for (int i = 0; i < 8; ++i) {
    int mG = bm + ty * 4 + (i & 3) + ((i >> 2) << 6);
    if (mG >= M) continue;
    const float* egrow = nullptr;
    if (MODE == 1) egrow = eg + (size_t)lastIdx[mG] * G4;
#pragma unroll
    for (int j = 0; j < 8; ++j) {
      int nG = bn + tx * 4 + (j & 3) + ((j >> 2) << 6);
      float v;
      if (MODE == 0) {
        v = acc[i][j];
        if (bias1) v = __fadd_rn(v, bias1[nG]);
      } else {
        // ref: (x@W_ih.T + h@W_hh.T) + (b_ih + b_hh), each add rounded once
        float bsum = __fadd_rn(bias1[nG], bias2[nG]);
        v = __fadd_rn(__fadd_rn(egrow[nG], acc[i][j]), bsum);
      }
      C[(size_t)mG * N + nG] = v;
    }
  }
}

// ---------------------------------------------------------------------------
// LSTM pointwise, pure f32, explicit rn ops (no FMA contraction).
// gate order i,f,g,o; c2=sig(f)*c+sig(i)*tanh(g); h2=sig(o)*tanh(c2)
// ---------------------------------------------------------------------------
__global__ __launch_bounds__(256) void lstm_pointwise(const float* __restrict__ gates,
                                                      float* __restrict__ h,
                                                      float* __restrict__ c) {
  int idx = blockIdx.x * 256 + threadIdx.x;
  int b = idx >> 10, jj = idx & 1023;
  const float* grow = gates + ((size_t)b << 12);
  float gi = grow[jj];
  float gf = grow[jj + 1024];
  float gg = grow[jj + 2048];
  float go = grow[jj + 3072];
  float cc = c[idx];
  float si = 1.0f / (__fadd_rn(1.0f, expf(-gi)));
  float sf = 1.0f / (__fadd_rn(1.0f, expf(-gf)));
  float so = 1.0f / (__fadd_rn(1.0f, expf(-go)));
  float c2 = __fadd_rn(__fmul_rn(sf, cc), __fmul_rn(si, tanhf(gg)));
  float h2 = __fmul_rn(so, tanhf(c2));
  c[idx] = c2;
  h[idx] = h2;
}

// ---------------------------------------------------------------------------
// logits (h2 @ W_act^T + b_act) + gumbel-max sampling + log_softmax + stats.
// All f32, ascending-k fmaf chain for the logit dot.
// Block = 256 threads = 4 waves; 8 batch rows per block (2 per wave, lane=class).
// ---------------------------------------------------------------------------
__global__ __launch_bounds__(256) void logits_sample(
    const float* __restrict__ h, const float* __restrict__ Wt,
    const float* __restrict__ b_act,
    const uint32_t* __restrict__ keyA, const uint32_t* __restrict__ keyB, int tstep,
    int* __restrict__ last, int* __restrict__ stopped,
    double* __restrict__ ent_sum, int* __restrict__ len_sum,
    float* __restrict__ out_lp, float* __restrict__ out_msg) {
  __shared__ float Ws[64][64];  // [k-in-panel][class]
  __shared__ float Hs[8][64];   // [local row][k-in-panel]
  const int tid = threadIdx.x;
  const int wave = tid >> 6;
  const int lane = tid & 63;
  const int rowBase = blockIdx.x * 8;

  float acc0 = 0.0f, acc1 = 0.0f;
  for (int kp = 0; kp < EDIM; kp += 64) {
    __syncthreads();
    {  // stage W panel (4096 floats)
      const float4* src = (const float4*)(Wt + (size_t)kp * ALPHA);
      float4* dst = (float4*)&Ws[0][0];
#pragma unroll
      for (int q = 0; q < 4; ++q) dst[tid + q * 256] = src[tid + q * 256];
    }
    if (tid < 128) {  // stage 8 h-rows x 64 k
      int rr = tid >> 4;
      int cc = (tid & 15) << 2;
      *(float4*)&Hs[rr][cc] = *(const float4*)(h + (size_t)(rowBase + rr) * EDIM + kp + cc);
    }
    __syncthreads();
#pragma unroll
    for (int kk = 0; kk < 64; ++kk) {   // ascending k
      float w = Ws[kk][lane];
      acc0 = fmaf(Hs[wave * 2 + 0][kk], w, acc0);
      acc1 = fmaf(Hs[wave * 2 + 1][kk], w, acc1);
    }
  }

  const float ba = b_act[lane];
  const uint32_t k0 = keyA[tstep], k1 = keyB[tstep];
  float logitv[2] = {__fadd_rn(acc0, ba), __fadd_rn(acc1, ba)};

#pragma unroll
  for (int rsel = 0; rsel < 2; ++rsel) {
    const int b = rowBase + wave * 2 + rsel;
    const float logit = logitv[rsel];

    // --- partitionable random_bits: elem m -> threefry(key, (0, m)), xor halves
    uint32_t m = ((uint32_t)b << 6) | (uint32_t)lane;
    uint32_t x0 = 0u, x1 = m;
    threefry2x32(k0, k1, x0, x1);
    uint32_t bits = x0 ^ x1;

    // bit-exact f32 uniform per jax: (bits>>9 | 1.0f) - 1; u = max(tiny, f+tiny)
    float f = __fsub_rn(__uint_as_float((bits >> 9) | 0x3F800000u), 1.0f);
    const float TINY = 1.17549435e-38f;
    float u = fmaxf(TINY, __fadd_rn(f, TINY));
    float gmb = -logf(-logf(u));
    float z = __fadd_rn(logit, gmb);

    // argmax (first index on ties)
    float bv = z;
    int bi = lane;
#pragma unroll
    for (int off = 32; off > 0; off >>= 1) {
      float ov = __shfl_xor(bv, off, 64);
      int oi = __shfl_xor(bi, off, 64);
      if (ov > bv || (ov == bv && oi < bi)) { bv = ov; bi = oi; }
    }

    // log_softmax: shifted - log(sum(exp(shifted)))
    float mx = logit;
#pragma unroll
    for (int off = 32; off > 0; off >>= 1) mx = fmaxf(mx, __shfl_xor(mx, off, 64));
    float sh = __fsub_rn(logit, mx);
    float e = expf(sh);
    float s = e;
#pragma unroll
    for (int off = 32; off > 0; off >>= 1) s = __fadd_rn(s, __shfl_xor(s, off, 64));
    float ls = logf(s);
    float logp = __fsub_rn(sh, ls);

    // entropy term: -sum(exp(logp)*logp)
    float term = __fmul_rn(expf(logp), logp);
    float ts = term;
#pragma unroll
    for (int off = 32; off > 0; off >>= 1) ts = __fadd_rn(ts, __shfl_xor(ts, off, 64));

    float lp_taken = __shfl(logp, bi, 64);  // uses UNMASKED sampled action

    int st = stopped[b];
    float live = st ? 0.0f : 1.0f;
    int act = st ? PAD_TOK : bi;
    int st2 = (st || act == EOS_TOK) ? 1 : 0;

    if (lane == 0) {
      out_msg[(size_t)b * TLEN + tstep] = (float)act;
      out_lp[(size_t)b * TLEN + tstep] = __fmul_rn(lp_taken, live);
      ent_sum[b] += (double)__fmul_rn(-ts, live);
      len_sum[b] += (act != PAD_TOK) ? 1 : 0;
      last[b] = act;
      stopped[b] = st2;
    }
  }
}

__global__ void finalize_kernel(const double* __restrict__ ent_sum,
                                const int* __restrict__ len_sum,
                                float* __restrict__ out_ent, float* __restrict__ out_len) {
  int b = blockIdx.x * 256 + threadIdx.x;
  if (b < BATCH) {
    out_ent[b] = (float)(ent_sum[b] / (double)len_sum[b]);
    out_len[b] = (float)len_sum[b];
  }
}

// ---------------------------------------------------------------------------
extern "C" void kernel_launch(void* const* d_in, const int* in_sizes, int n_in,
                              void* d_out, int out_size, void* d_ws, size_t ws_size,
                              hipStream_t stream) {
  const float* encoded = (const float*)d_in[0];
  const float* embed = (const float*)d_in[1];
  const float* W_ih = (const float*)d_in[2];
  const float* W_hh = (const float*)d_in[3];
  const float* b_ih = (const float*)d_in[4];
  const float* b_hh = (const float*)d_in[5];
  const float* W_cell = (const float*)d_in[6];
  const float* b_cell = (const float*)d_in[7];
  const float* W_hid = (const float*)d_in[8];
  const float* b_hid = (const float*)d_in[9];
  const float* W_act = (const float*)d_in[10];
  const float* b_act = (const float*)d_in[11];

  float* out = (float*)d_out;
  float* out_ent = out;                           // [4096]
  float* out_lp = out + BATCH;                    // [4096*20]
  float* out_msg = out + BATCH + BATCH * TLEN;    // [4096*20]
  float* out_len = out + BATCH + 2 * BATCH * TLEN;// [4096]

  char* ws = (char*)d_ws;
  size_t off = 0;
  auto alloc = [&](size_t bytes) -> void* {
    void* p = ws + off;
    off = (off + bytes + 255) & ~(size_t)255;
    return p;
  };
  float* h = (float*)alloc(sizeof(float) * (size_t)BATCH * EDIM);       // 16 MB
  float* c = (float*)alloc(sizeof(float) * (size_t)BATCH * EDIM);       // 16 MB
  float* gates = (float*)alloc(sizeof(float) * (size_t)BATCH * G4);     // 64 MB
  float* eg = (float*)alloc(sizeof(float) * 66 * G4);                   // 1 MB (raw s1)
  float* Wt = (float*)alloc(sizeof(float) * EDIM * ALPHA);              // 256 KB
  uint32_t* keyA = (uint32_t*)alloc(sizeof(uint32_t) * TLEN);
  uint32_t* keyB = (uint32_t*)alloc(sizeof(uint32_t) * TLEN);
  int* last = (int*)alloc(sizeof(int) * BATCH);
  int* stopped = (int*)alloc(sizeof(int) * BATCH);
  double* ent_s = (double*)alloc(sizeof(double) * BATCH);
  int* len_s = (int*)alloc(sizeof(int) * BATCH);
  (void)ws_size; (void)in_sizes; (void)n_in; (void)out_size;

  init_kernel<<<16, 256, 0, stream>>>(keyA, keyB, last, stopped, ent_s, len_s);
  transpose_wact<<<(ALPHA * EDIM) / 256, 256, 0, stream>>>(W_act, Wt);

  // s1 table: eg = embed @ W_ih^T  (NO bias — ref adds bias after both gemms)
  gemm_nt<0><<<dim3(32, 1), 256, 0, stream>>>(embed, W_ih, eg, 66, G4, EDIM,
                                              nullptr, nullptr, nullptr, nullptr);
  // h0 = encoded @ W_cell^T + b_cell ; c0 = encoded @ W_hid^T + b_hid
  gemm_nt<0><<<dim3(8, 32), 256, 0, stream>>>(encoded, W_cell, h, BATCH, EDIM, EDIM,
                                              b_cell, nullptr, nullptr, nullptr);
  gemm_nt<0><<<dim3(8, 32), 256, 0, stream>>>(encoded, W_hid, c, BATCH, EDIM, EDIM,
                                              b_hid, nullptr, nullptr, nullptr);

  for (int t = 0; t < TLEN; ++t) {
    // gates = (eg[last] + h @ W_hh^T) + (b_ih + b_hh)
    gemm_nt<1><<<dim3(32, 32), 256, 0, stream>>>(h, W_hh, gates, BATCH, G4, EDIM,
                                                 b_ih, b_hh, eg, last);
    lstm_pointwise<<<(BATCH * EDIM) / 256, 256, 0, stream>>>(gates, h, c);
    logits_sample<<<BATCH / 8, 256, 0, stream>>>(h, Wt, b_act, keyA, keyB, t,
                                                 last, stopped, ent_s, len_s,
                                                 out_lp, out_msg);
  }
  finalize_kernel<<<16, 256, 0, stream>>>(ent_s, len_s, out_ent, out_len);
}